// Round 8
// baseline (4513.232 us; speedup 1.0000x reference)
//
#include <hip/hip_runtime.h>
#include <stdint.h>
#include <stddef.h>

typedef unsigned long long u64;

#define NBATCH 8
#define NPTS   8192
#define SG     2048
#define KS     32
#define NGRP   (NBATCH*SG)      // 16384
#define MROWS  (NGRP*KS)        // 524288

// ---- ALL scratch in module-static device globals (~20 MiB): immune to ws_size ----
__device__ float4 g_p4[NBATCH*NPTS];          // 1 MiB  {x,y,z,|p|^2}
__device__ float  g_cx[NGRP], g_cy[NGRP], g_cz[NGRP];
__device__ int    g_ball[(size_t)NGRP*KS];    // 2 MiB
__device__ double g_stats[3*128*256];         // 768 KiB  [stage][bucket][sum|sq]
__device__ float  g_A[256], g_Bv[256];        // BN scale/shift: L0 @0, L1 @64, L2 @128
__device__ float  g_mmax[(size_t)NGRP*128];   // 8 MiB  raw y2 per-group max
__device__ float  g_mmin[(size_t)NGRP*128];   // 8 MiB  raw y2 per-group min

// ---------------- K_zero: zero the stats accumulators ----------------
__global__ __launch_bounds__(256) void k_zero(){
  int idx = blockIdx.x*256 + threadIdx.x;
  if (idx < 3*128*256) g_stats[idx] = 0.0;
}

// ---------------- K_pre: f32 xyz -> packed float4 ----------------
__global__ __launch_bounds__(256) void k_pre(const float* __restrict__ xyz){
#pragma clang fp contract(off)
  int idx = blockIdx.x*256 + threadIdx.x;
  if (idx >= NBATCH*NPTS) return;
  float x = xyz[idx*3+0];
  float y = xyz[idx*3+1];
  float z = xyz[idx*3+2];
  float xx = x*x; float yy = y*y; float zz = z*z;
  float s2 = (xx + yy) + zz;
  g_p4[idx] = make_float4(x,y,z,s2);
}

// ---------------- K_fps: farthest point sampling (1 block = 1 batch) ----------------
// f32 mirror of ref ((dx*dx + dy*dy) + dz*dz, no fma) — PASSED round 3+, do not touch.
__global__ __launch_bounds__(512) void k_fps(const int* __restrict__ start, float* __restrict__ out_xyz){
  const int b = blockIdx.x;
  const int t = threadIdx.x;
  const int base = b*NPTS;
  __shared__ float rv[2][8];
  __shared__ int   ri[2][8];
  float px[16],py[16],pz[16],dist[16];
#pragma unroll
  for (int i=0;i<16;i++){
    float4 p = g_p4[base + i*512 + t];
    px[i]=p.x; py[i]=p.y; pz[i]=p.z; dist[i]=1e10f;
  }
  int far = start[b];
  float4 fc = g_p4[base+far];
  if (t==0){
    g_cx[b*SG]=fc.x; g_cy[b*SG]=fc.y; g_cz[b*SG]=fc.z;
    size_t o = (size_t)(b*SG)*3;
    out_xyz[o+0]=fc.x; out_xyz[o+1]=fc.y; out_xyz[o+2]=fc.z;
  }
  const int lane = t & 63;
  for (int it=1; it<SG; ++it){
    float bv = -1.0f; int bi = 0;
    {
#pragma clang fp contract(off)
#pragma unroll
      for (int i=0;i<16;i++){
        float dx = px[i]-fc.x;
        float dy = py[i]-fc.y;
        float dz = pz[i]-fc.z;
        float a0 = dx*dx; float a1 = dy*dy; float a2 = dz*dz;
        float d  = (a0 + a1) + a2;
        float nd = fminf(dist[i], d);
        dist[i] = nd;
        if (nd > bv){ bv = nd; bi = i; }
      }
    }
    int gi = bi*512 + t;
#pragma unroll
    for (int off=32; off>=1; off>>=1){
      float ov = __shfl_down(bv, off);
      int   oi = __shfl_down(gi, off);
      if (ov > bv || (ov == bv && oi < gi)) { bv = ov; gi = oi; }
    }
    const int pb = it & 1;
    if (lane==0){ rv[pb][t>>6]=bv; ri[pb][t>>6]=gi; }
    __syncthreads();
    float v = rv[pb][lane & 7]; int gw = ri[pb][lane & 7];
#pragma unroll
    for (int off=4; off>=1; off>>=1){
      float v2 = __shfl_xor(v, off);
      int   g2 = __shfl_xor(gw, off);
      if (v2 > v || (v2 == v && g2 < gw)) { v = v2; gw = g2; }
    }
    far = gw;
    fc = g_p4[base+far];
    if (t==0){
      g_cx[b*SG+it]=fc.x; g_cy[b*SG+it]=fc.y; g_cz[b*SG+it]=fc.z;
      size_t o = (size_t)(b*SG+it)*3;
      out_xyz[o+0]=fc.x; out_xyz[o+1]=fc.y; out_xyz[o+2]=fc.z;
    }
  }
}

// ---------------- K_ball: expansion form, FMA-ascending dot (BLAS sgemm / Eigen gebp model) ----------------
// E = fma(cz,z, fma(cy,y, cx*x)); sq = (s1+s2) - 2*E
__global__ __launch_bounds__(256) void k_ball(){
  const int g = blockIdx.x*4 + (threadIdx.x>>6);
  const int lane = threadIdx.x & 63;
  const int b = g >> 11;
  const float4* pb4 = g_p4 + b*NPTS;
  float cxv = g_cx[g], cyv = g_cy[g], czv = g_cz[g];
  float s1;
  {
#pragma clang fp contract(off)
    float a = cxv*cxv; float bb = cyv*cyv; float cc = czv*czv;
    s1 = (a + bb) + cc;                  // np.sum ascending
  }
  const float R2 = 0.04f;
  int filled = 0, firstn = -1;
  for (int n0=0; n0<NPTS && filled<KS; n0+=64){
    float4 p = pb4[n0+lane];
    float sq;
    {
#pragma clang fp contract(off)
      float dt = cxv*p.x;                // = fma(cx,x,0): single rounding
      dt = fmaf(cyv, p.y, dt);           // FMA ascending k, as BLAS microkernels do
      dt = fmaf(czv, p.z, dt);
      float ss = s1 + p.w;               // s1 + s2
      sq = ss - 2.0f*dt;                 // (s1+s2) - 2*E
    }
    bool mem = !(sq > R2);
    u64 mk = __ballot(mem);
    if (firstn < 0 && mk) firstn = n0 + (__ffsll((unsigned long long)mk) - 1);
    int pos = filled + (int)__popcll(mk & ((1ull<<lane)-1ull));
    if (mem && pos < KS) g_ball[(size_t)g*KS + pos] = n0 + lane;
    filled += (int)__popcll(mk);
  }
  for (int s = filled + lane; s < KS; s += 64) g_ball[(size_t)g*KS+s] = firstn;
}

// ---------------- K_mlp<STAGE>: fused recompute MLP passes, 1 block = 1 group ----------------
// STAGE 0: gather + L0 -> stats0
// STAGE 1: gather + L0 + BN0/ReLU + L1 -> stats1
// STAGE 2: gather + L0 + BN0 + L1 + BN1 + L2 -> stats2 + per-group max/min of raw y2
template<int STAGE>
__global__ __launch_bounds__(256) void k_mlp(
    const float* __restrict__ points,
    const float* __restrict__ W0, const float* __restrict__ B0v,
    const float* __restrict__ W1, const float* __restrict__ B1v,
    const float* __restrict__ W2, const float* __restrict__ B2v){
  constexpr int COUT = (STAGE==2)?128:64;
  double* stats = g_stats + (size_t)STAGE*128*256;
  const int g = blockIdx.x, tid = threadIdx.x;
  const int b = g >> 11;
  __shared__ __align__(16) float xt[32][68];
  __shared__ __align__(16) float xn[(STAGE>=1)?32:1][68];
  __shared__ __align__(16) float w0s[68][64];
  __shared__ __align__(16) float w1s[(STAGE>=1)?64:1][64];
  __shared__ __align__(16) float w2s[(STAGE>=2)?64:1][128];
  __shared__ float wsum[4][COUT], wsq[4][COUT];
  __shared__ float wmx[(STAGE==2)?4:1][128], wmn[(STAGE==2)?4:1][128];

  for (int i = tid; i < 67*64; i += 256) w0s[i>>6][i&63] = W0[i];
  if (tid < 64) w0s[67][tid] = 0.f;
  if (STAGE>=1){ for (int i = tid; i < 64*64; i += 256) w1s[i>>6][i&63] = W1[i]; }
  if (STAGE>=2){ for (int i = tid; i < 64*128; i += 256) w2s[i>>7][i&127] = W2[i]; }

  if (tid < 32){
    int n = g_ball[(size_t)g*KS + tid];
    float4 p = g_p4[b*NPTS + n];
    xt[tid][0] = p.x - g_cx[g];
    xt[tid][1] = p.y - g_cy[g];
    xt[tid][2] = p.z - g_cz[g];
    xt[tid][67] = 0.f;
  }
  {
    int k = tid >> 3, j = tid & 7;   // 32 rows x 8 threads, 8 floats each
    int n = g_ball[(size_t)g*KS + k];
    const float4* pr = (const float4*)(points + ((size_t)(b*NPTS + n))*64);
    float4 v0 = pr[j*2], v1 = pr[j*2+1];
    int c0 = 3 + j*8;
    xt[k][c0+0]=v0.x; xt[k][c0+1]=v0.y; xt[k][c0+2]=v0.z; xt[k][c0+3]=v0.w;
    xt[k][c0+4]=v1.x; xt[k][c0+5]=v1.y; xt[k][c0+6]=v1.z; xt[k][c0+7]=v1.w;
  }
  __syncthreads();

  const int k0 = (tid >> 4) * 2;
  const int d0 = (tid & 15) * 4;
  const int lane = tid & 63, w = tid >> 6;

  // ---- L0: 32x67 @ 67x64 ----
  float acc0[4] = {0.f,0.f,0.f,0.f};
  float acc1[4] = {0.f,0.f,0.f,0.f};
#pragma unroll
  for (int cq = 0; cq < 17; ++cq){
    const int c = cq*4;
    float xa[4], xb[4], r0[4], r1[4], r2[4], r3[4];
    *(float4*)xa = *(const float4*)&xt[k0][c];
    *(float4*)xb = *(const float4*)&xt[k0+1][c];
    *(float4*)r0 = *(const float4*)&w0s[c+0][d0];
    *(float4*)r1 = *(const float4*)&w0s[c+1][d0];
    *(float4*)r2 = *(const float4*)&w0s[c+2][d0];
    *(float4*)r3 = *(const float4*)&w0s[c+3][d0];
#pragma unroll
    for (int j=0;j<4;j++){
      acc0[j] = fmaf(xa[0], r0[j], acc0[j]);
      acc0[j] = fmaf(xa[1], r1[j], acc0[j]);
      acc0[j] = fmaf(xa[2], r2[j], acc0[j]);
      acc0[j] = fmaf(xa[3], r3[j], acc0[j]);
      acc1[j] = fmaf(xb[0], r0[j], acc1[j]);
      acc1[j] = fmaf(xb[1], r1[j], acc1[j]);
      acc1[j] = fmaf(xb[2], r2[j], acc1[j]);
      acc1[j] = fmaf(xb[3], r3[j], acc1[j]);
    }
  }
#pragma unroll
  for (int j=0;j<4;j++){ float bv = B0v[d0+j]; acc0[j] += bv; acc1[j] += bv; }

  if constexpr (STAGE == 0){
    float s[4], q[4];
#pragma unroll
    for (int j=0;j<4;j++){ s[j] = acc0[j]+acc1[j]; q[j] = acc0[j]*acc0[j] + acc1[j]*acc1[j]; }
#pragma unroll
    for (int j=0;j<4;j++){
      s[j] += __shfl_down(s[j],32); s[j] += __shfl_down(s[j],16);
      q[j] += __shfl_down(q[j],32); q[j] += __shfl_down(q[j],16);
    }
    if (lane < 16){
#pragma unroll
      for (int j=0;j<4;j++){ wsum[w][lane*4+j] = s[j]; wsq[w][lane*4+j] = q[j]; }
    }
    __syncthreads();
    if (tid < 64){
      float S = wsum[0][tid]+wsum[1][tid]+wsum[2][tid]+wsum[3][tid];
      float Q = wsq[0][tid]+wsq[1][tid]+wsq[2][tid]+wsq[3][tid];
      int bucket = g & 127;
      atomicAdd(&stats[(size_t)bucket*256 + tid], (double)S);
      atomicAdd(&stats[(size_t)bucket*256 + 128 + tid], (double)Q);
    }
  } else {
    // BN0 + ReLU -> xn
#pragma unroll
    for (int j=0;j<4;j++){
      xn[k0][d0+j]   = fmaxf(fmaf(acc0[j], g_A[d0+j], g_Bv[d0+j]), 0.f);
      xn[k0+1][d0+j] = fmaxf(fmaf(acc1[j], g_A[d0+j], g_Bv[d0+j]), 0.f);
    }
    __syncthreads();

    // ---- L1: 32x64 @ 64x64 ----
    float bc0[4] = {0.f,0.f,0.f,0.f};
    float bc1[4] = {0.f,0.f,0.f,0.f};
#pragma unroll
    for (int cq = 0; cq < 16; ++cq){
      const int c = cq*4;
      float xa[4], xb[4], r0[4], r1[4], r2[4], r3[4];
      *(float4*)xa = *(const float4*)&xn[k0][c];
      *(float4*)xb = *(const float4*)&xn[k0+1][c];
      *(float4*)r0 = *(const float4*)&w1s[c+0][d0];
      *(float4*)r1 = *(const float4*)&w1s[c+1][d0];
      *(float4*)r2 = *(const float4*)&w1s[c+2][d0];
      *(float4*)r3 = *(const float4*)&w1s[c+3][d0];
#pragma unroll
      for (int j=0;j<4;j++){
        bc0[j] = fmaf(xa[0], r0[j], bc0[j]);
        bc0[j] = fmaf(xa[1], r1[j], bc0[j]);
        bc0[j] = fmaf(xa[2], r2[j], bc0[j]);
        bc0[j] = fmaf(xa[3], r3[j], bc0[j]);
        bc1[j] = fmaf(xb[0], r0[j], bc1[j]);
        bc1[j] = fmaf(xb[1], r1[j], bc1[j]);
        bc1[j] = fmaf(xb[2], r2[j], bc1[j]);
        bc1[j] = fmaf(xb[3], r3[j], bc1[j]);
      }
    }
#pragma unroll
    for (int j=0;j<4;j++){ float bv = B1v[d0+j]; bc0[j] += bv; bc1[j] += bv; }

    if constexpr (STAGE == 1){
      float s[4], q[4];
#pragma unroll
      for (int j=0;j<4;j++){ s[j] = bc0[j]+bc1[j]; q[j] = bc0[j]*bc0[j] + bc1[j]*bc1[j]; }
#pragma unroll
      for (int j=0;j<4;j++){
        s[j] += __shfl_down(s[j],32); s[j] += __shfl_down(s[j],16);
        q[j] += __shfl_down(q[j],32); q[j] += __shfl_down(q[j],16);
      }
      if (lane < 16){
#pragma unroll
        for (int j=0;j<4;j++){ wsum[w][lane*4+j] = s[j]; wsq[w][lane*4+j] = q[j]; }
      }
      __syncthreads();
      if (tid < 64){
        float S = wsum[0][tid]+wsum[1][tid]+wsum[2][tid]+wsum[3][tid];
        float Q = wsq[0][tid]+wsq[1][tid]+wsq[2][tid]+wsq[3][tid];
        int bucket = g & 127;
        atomicAdd(&stats[(size_t)bucket*256 + tid], (double)S);
        atomicAdd(&stats[(size_t)bucket*256 + 128 + tid], (double)Q);
      }
    } else {
      // BN1 + ReLU -> xt (dead after L0)
#pragma unroll
      for (int j=0;j<4;j++){
        xt[k0][d0+j]   = fmaxf(fmaf(bc0[j], g_A[64+d0+j], g_Bv[64+d0+j]), 0.f);
        xt[k0+1][d0+j] = fmaxf(fmaf(bc1[j], g_A[64+d0+j], g_Bv[64+d0+j]), 0.f);
      }
      __syncthreads();

      // ---- L2: 32x64 @ 64x128 ----
      const int e0 = (tid & 15) * 8;
      float c0[8] = {0.f,0.f,0.f,0.f,0.f,0.f,0.f,0.f};
      float c1[8] = {0.f,0.f,0.f,0.f,0.f,0.f,0.f,0.f};
#pragma unroll
      for (int cq = 0; cq < 16; ++cq){
        const int c = cq*4;
        float xa[4], xb[4], r0[8], r1[8], r2[8], r3[8];
        *(float4*)xa = *(const float4*)&xt[k0][c];
        *(float4*)xb = *(const float4*)&xt[k0+1][c];
        *(float4*)&r0[0] = *(const float4*)&w2s[c+0][e0]; *(float4*)&r0[4] = *(const float4*)&w2s[c+0][e0+4];
        *(float4*)&r1[0] = *(const float4*)&w2s[c+1][e0]; *(float4*)&r1[4] = *(const float4*)&w2s[c+1][e0+4];
        *(float4*)&r2[0] = *(const float4*)&w2s[c+2][e0]; *(float4*)&r2[4] = *(const float4*)&w2s[c+2][e0+4];
        *(float4*)&r3[0] = *(const float4*)&w2s[c+3][e0]; *(float4*)&r3[4] = *(const float4*)&w2s[c+3][e0+4];
#pragma unroll
        for (int j=0;j<8;j++){
          c0[j] = fmaf(xa[0], r0[j], c0[j]);
          c0[j] = fmaf(xa[1], r1[j], c0[j]);
          c0[j] = fmaf(xa[2], r2[j], c0[j]);
          c0[j] = fmaf(xa[3], r3[j], c0[j]);
          c1[j] = fmaf(xb[0], r0[j], c1[j]);
          c1[j] = fmaf(xb[1], r1[j], c1[j]);
          c1[j] = fmaf(xb[2], r2[j], c1[j]);
          c1[j] = fmaf(xb[3], r3[j], c1[j]);
        }
      }
#pragma unroll
      for (int j=0;j<8;j++){ float bv = B2v[e0+j]; c0[j] += bv; c1[j] += bv; }

      float s[8], q[8], mx[8], mn[8];
#pragma unroll
      for (int j=0;j<8;j++){
        s[j] = c0[j]+c1[j]; q[j] = c0[j]*c0[j] + c1[j]*c1[j];
        mx[j] = fmaxf(c0[j], c1[j]); mn[j] = fminf(c0[j], c1[j]);
      }
#pragma unroll
      for (int j=0;j<8;j++){
        s[j] += __shfl_down(s[j],32); s[j] += __shfl_down(s[j],16);
        q[j] += __shfl_down(q[j],32); q[j] += __shfl_down(q[j],16);
        mx[j] = fmaxf(mx[j], __shfl_xor(mx[j],16)); mx[j] = fmaxf(mx[j], __shfl_xor(mx[j],32));
        mn[j] = fminf(mn[j], __shfl_xor(mn[j],16)); mn[j] = fminf(mn[j], __shfl_xor(mn[j],32));
      }
      if (lane < 16){
#pragma unroll
        for (int j=0;j<8;j++){
          wsum[w][lane*8+j] = s[j]; wsq[w][lane*8+j] = q[j];
          wmx[w][lane*8+j] = mx[j]; wmn[w][lane*8+j] = mn[j];
        }
      }
      __syncthreads();
      if (tid < 128){
        float S = wsum[0][tid]+wsum[1][tid]+wsum[2][tid]+wsum[3][tid];
        float Q = wsq[0][tid]+wsq[1][tid]+wsq[2][tid]+wsq[3][tid];
        float MX = fmaxf(fmaxf(wmx[0][tid],wmx[1][tid]), fmaxf(wmx[2][tid],wmx[3][tid]));
        float MN = fminf(fminf(wmn[0][tid],wmn[1][tid]), fminf(wmn[2][tid],wmn[3][tid]));
        g_mmax[(size_t)g*128 + tid] = MX;
        g_mmin[(size_t)g*128 + tid] = MN;
        int bucket = g & 127;
        atomicAdd(&stats[(size_t)bucket*256 + tid], (double)S);
        atomicAdd(&stats[(size_t)bucket*256 + 128 + tid], (double)Q);
      }
    }
  }
}

// ---------------- K_stats: finalize BN scale/shift ----------------
__global__ void k_stats(int stage, const float* __restrict__ gamma,
                        const float* __restrict__ beta, int aoff, int cout){
  int c = threadIdx.x;
  if (c >= cout) return;
  const double* stats = g_stats + (size_t)stage*128*256;
  double S=0.0, Q=0.0;
  for (int k=0;k<128;k++){ S += stats[(size_t)k*256 + c]; Q += stats[(size_t)k*256 + 128 + c]; }
  const double M = (double)MROWS;
  double mean = S / M;
  double var  = Q / M - mean*mean;
  double inv  = 1.0 / sqrt(var + 1e-5);
  double a    = (double)gamma[c] * inv;
  g_A[aoff+c]  = (float)a;
  g_Bv[aoff+c] = (float)((double)beta[c] - mean * a);
}

// ---------------- K_final: BN2 on max (or min if a<0) + ReLU ----------------
__global__ __launch_bounds__(256) void k_final(float* __restrict__ outp){
  int idx = blockIdx.x*256 + threadIdx.x;   // 16384*128 = 2M
  int d = idx & 127;
  float a = g_A[128+d], b = g_Bv[128+d];
  float y = (a >= 0.f) ? g_mmax[idx] : g_mmin[idx]; // BN per-channel linear
  float v = fmaf(y, a, b);
  outp[idx] = fmaxf(v, 0.f);
}

extern "C" void kernel_launch(void* const* d_in, const int* in_sizes, int n_in,
                              void* d_out, int out_size, void* d_ws, size_t ws_size,
                              hipStream_t stream) {
  (void)in_sizes; (void)n_in; (void)out_size; (void)d_ws; (void)ws_size;
  const float* xyz    = (const float*)d_in[0];
  const float* points = (const float*)d_in[1];
  const int*   start  = (const int*)d_in[2];
  const float* W0 = (const float*)d_in[3];  const float* b0 = (const float*)d_in[4];
  const float* g0 = (const float*)d_in[5];  const float* be0= (const float*)d_in[6];
  const float* W1 = (const float*)d_in[7];  const float* b1 = (const float*)d_in[8];
  const float* g1 = (const float*)d_in[9];  const float* be1= (const float*)d_in[10];
  const float* W2 = (const float*)d_in[11]; const float* b2 = (const float*)d_in[12];
  const float* g2 = (const float*)d_in[13]; const float* be2= (const float*)d_in[14];

  float* out_xyz = (float*)d_out;
  float* out_pts = (float*)d_out + (size_t)NBATCH*SG*3;

  k_zero <<<384, 256, 0, stream>>>();
  k_pre  <<<256, 256, 0, stream>>>(xyz);
  k_fps  <<<NBATCH, 512, 0, stream>>>(start, out_xyz);
  k_ball <<<4096, 256, 0, stream>>>();

  k_mlp<0><<<NGRP, 256, 0, stream>>>(points, W0, b0, W1, b1, W2, b2);
  k_stats<<<1, 128, 0, stream>>>(0, g0, be0, 0, 64);
  k_mlp<1><<<NGRP, 256, 0, stream>>>(points, W0, b0, W1, b1, W2, b2);
  k_stats<<<1, 128, 0, stream>>>(1, g1, be1, 64, 64);
  k_mlp<2><<<NGRP, 256, 0, stream>>>(points, W0, b0, W1, b1, W2, b2);
  k_stats<<<1, 128, 0, stream>>>(2, g2, be2, 128, 128);
  k_final<<<8192, 256, 0, stream>>>(out_pts);
}

// Round 9
// 3162.663 us; speedup vs baseline: 1.4270x; 1.4270x over previous
//
#include <hip/hip_runtime.h>
#include <stdint.h>
#include <stddef.h>

typedef unsigned long long u64;
typedef unsigned int u32;

#define NBATCH 8
#define NPTS   8192
#define SG     2048
#define KS     32
#define NGRP   (NBATCH*SG)      // 16384
#define MROWS  (NGRP*KS)        // 524288

// ---- ALL scratch in module-static device globals: immune to ws_size ----
__device__ float4 g_p4[NBATCH*NPTS];          // 1 MiB  {x,y,z,|p|^2}
__device__ float  g_cx[NGRP], g_cy[NGRP], g_cz[NGRP];
__device__ int    g_ball[(size_t)NGRP*KS];    // 2 MiB
__device__ double g_stats[3*128*256];         // 768 KiB
__device__ float  g_A[256], g_Bv[256];        // BN scale/shift: L0 @0, L1 @64, L2 @128
__device__ float  g_mmax[(size_t)NGRP*128];   // 8 MiB
__device__ float  g_mmin[(size_t)NGRP*128];   // 8 MiB
__device__ float  g_y0[(size_t)MROWS*64];     // 134 MiB raw L0 output
__device__ float  g_y1[(size_t)MROWS*64];     // 134 MiB raw L1 output

// ---------------- K_zero ----------------
__global__ __launch_bounds__(256) void k_zero(){
  int idx = blockIdx.x*256 + threadIdx.x;
  if (idx < 3*128*256) g_stats[idx] = 0.0;
}

// ---------------- K_pre ----------------
__global__ __launch_bounds__(256) void k_pre(const float* __restrict__ xyz){
#pragma clang fp contract(off)
  int idx = blockIdx.x*256 + threadIdx.x;
  if (idx >= NBATCH*NPTS) return;
  float x = xyz[idx*3+0];
  float y = xyz[idx*3+1];
  float z = xyz[idx*3+2];
  float xx = x*x; float yy = y*y; float zz = z*z;
  float s2 = (xx + yy) + zz;
  g_p4[idx] = make_float4(x,y,z,s2);
}

// ---------------- K_fps: 256 threads, 32 pts/thread, u64-key reduce ----------------
// Distance math identical bits to the round-7 PASSING version:
//   d = ((px-cx)^2 + (py-cy)^2) + (pz-cz)^2, no fma; dist = fminf(dist, d)
// Argmax with first-index tie-break via key = (dist_bits<<32)|(8191-g):
//   dist>=0 so f32 bit pattern order == value order; larger key == larger dist,
//   then smaller global index. Key uniqueness guaranteed by the index field.
__global__ __launch_bounds__(256, 1) void k_fps(const int* __restrict__ start, float* __restrict__ out_xyz){
  const int b = blockIdx.x;
  const int t = threadIdx.x;
  const int base = b*NPTS;
  __shared__ u64 wk[2][4];
  float px[32],py[32],pz[32],dist[32];
#pragma unroll
  for (int i=0;i<32;i++){
    float4 p = g_p4[base + i*256 + t];
    px[i]=p.x; py[i]=p.y; pz[i]=p.z; dist[i]=1e10f;
  }
  int far = start[b];
  float4 fc = g_p4[base+far];
  if (t==0){
    g_cx[b*SG]=fc.x; g_cy[b*SG]=fc.y; g_cz[b*SG]=fc.z;
    size_t o = (size_t)(b*SG)*3;
    out_xyz[o+0]=fc.x; out_xyz[o+1]=fc.y; out_xyz[o+2]=fc.z;
  }
  const int lane = t & 63, w = t >> 6;
  for (int it=1; it<SG; ++it){
    float bv = -1.0f; int bi = 0;
    {
#pragma clang fp contract(off)
#pragma unroll
      for (int i=0;i<32;i++){
        float dx = px[i]-fc.x;
        float dy = py[i]-fc.y;
        float dz = pz[i]-fc.z;
        float a0 = dx*dx; float a1 = dy*dy; float a2 = dz*dz;
        float d  = (a0 + a1) + a2;
        float nd = fminf(dist[i], d);
        dist[i] = nd;
        if (nd > bv){ bv = nd; bi = i; }   // ascending i == ascending g for this thread
      }
    }
    int gi = bi*256 + t;
    u64 key = ((u64)__float_as_uint(bv) << 32) | (u32)(NPTS-1 - gi);
#pragma unroll
    for (int off=32; off>=1; off>>=1){
      u64 k2 = __shfl_down(key, off);
      if (k2 > key) key = k2;
    }
    const int pb = it & 1;
    if (lane==0) wk[pb][w] = key;
    __syncthreads();
    u64 k0 = wk[pb][0], k1 = wk[pb][1], k2 = wk[pb][2], k3 = wk[pb][3];
    u64 ka = (k0 > k1) ? k0 : k1;
    u64 kb = (k2 > k3) ? k2 : k3;
    u64 km = (ka > kb) ? ka : kb;
    far = NPTS-1 - (int)(km & 0xffffffffu);
    fc = g_p4[base+far];
    if (t==0){
      g_cx[b*SG+it]=fc.x; g_cy[b*SG+it]=fc.y; g_cz[b*SG+it]=fc.z;
      size_t o = (size_t)(b*SG+it)*3;
      out_xyz[o+0]=fc.x; out_xyz[o+1]=fc.y; out_xyz[o+2]=fc.z;
    }
  }
}

// ---------------- K_ball: expansion form, FMA-ascending dot (PASSED r7, do not touch) ----------------
__global__ __launch_bounds__(256) void k_ball(){
  const int g = blockIdx.x*4 + (threadIdx.x>>6);
  const int lane = threadIdx.x & 63;
  const int b = g >> 11;
  const float4* pb4 = g_p4 + b*NPTS;
  float cxv = g_cx[g], cyv = g_cy[g], czv = g_cz[g];
  float s1;
  {
#pragma clang fp contract(off)
    float a = cxv*cxv; float bb = cyv*cyv; float cc = czv*czv;
    s1 = (a + bb) + cc;
  }
  const float R2 = 0.04f;
  int filled = 0, firstn = -1;
  for (int n0=0; n0<NPTS && filled<KS; n0+=64){
    float4 p = pb4[n0+lane];
    float sq;
    {
#pragma clang fp contract(off)
      float dt = cxv*p.x;
      dt = fmaf(cyv, p.y, dt);
      dt = fmaf(czv, p.z, dt);
      float ss = s1 + p.w;
      sq = ss - 2.0f*dt;
    }
    bool mem = !(sq > R2);
    u64 mk = __ballot(mem);
    if (firstn < 0 && mk) firstn = n0 + (__ffsll((unsigned long long)mk) - 1);
    int pos = filled + (int)__popcll(mk & ((1ull<<lane)-1ull));
    if (mem && pos < KS) g_ball[(size_t)g*KS + pos] = n0 + lane;
    filled += (int)__popcll(mk);
  }
  for (int s = filled + lane; s < KS; s += 64) g_ball[(size_t)g*KS+s] = firstn;
}

// ---------------- K_mlpA: gather + L0 -> Y0 (raw f32) + stats0 ----------------
__global__ __launch_bounds__(256) void k_mlpA(
    const float* __restrict__ points,
    const float* __restrict__ W0, const float* __restrict__ B0v){
  double* stats = g_stats;
  const int g = blockIdx.x, tid = threadIdx.x;
  const int b = g >> 11;
  __shared__ __align__(16) float xt[32][68];
  __shared__ __align__(16) float w0s[68][64];
  __shared__ float wsum[4][64], wsq[4][64];

  for (int i = tid; i < 67*64; i += 256) w0s[i>>6][i&63] = W0[i];
  if (tid < 64) w0s[67][tid] = 0.f;

  if (tid < 32){
    int n = g_ball[(size_t)g*KS + tid];
    float4 p = g_p4[b*NPTS + n];
    xt[tid][0] = p.x - g_cx[g];
    xt[tid][1] = p.y - g_cy[g];
    xt[tid][2] = p.z - g_cz[g];
    xt[tid][67] = 0.f;
  }
  {
    int k = tid >> 3, j = tid & 7;
    int n = g_ball[(size_t)g*KS + k];
    const float4* pr = (const float4*)(points + ((size_t)(b*NPTS + n))*64);
    float4 v0 = pr[j*2], v1 = pr[j*2+1];
    int c0 = 3 + j*8;
    xt[k][c0+0]=v0.x; xt[k][c0+1]=v0.y; xt[k][c0+2]=v0.z; xt[k][c0+3]=v0.w;
    xt[k][c0+4]=v1.x; xt[k][c0+5]=v1.y; xt[k][c0+6]=v1.z; xt[k][c0+7]=v1.w;
  }
  __syncthreads();

  const int k0 = (tid >> 4) * 2;
  const int d0 = (tid & 15) * 4;
  const int lane = tid & 63, w = tid >> 6;

  float acc0[4] = {0.f,0.f,0.f,0.f};
  float acc1[4] = {0.f,0.f,0.f,0.f};
#pragma unroll
  for (int cq = 0; cq < 17; ++cq){
    const int c = cq*4;
    float xa[4], xb[4], r0[4], r1[4], r2[4], r3[4];
    *(float4*)xa = *(const float4*)&xt[k0][c];
    *(float4*)xb = *(const float4*)&xt[k0+1][c];
    *(float4*)r0 = *(const float4*)&w0s[c+0][d0];
    *(float4*)r1 = *(const float4*)&w0s[c+1][d0];
    *(float4*)r2 = *(const float4*)&w0s[c+2][d0];
    *(float4*)r3 = *(const float4*)&w0s[c+3][d0];
#pragma unroll
    for (int j=0;j<4;j++){
      acc0[j] = fmaf(xa[0], r0[j], acc0[j]);
      acc0[j] = fmaf(xa[1], r1[j], acc0[j]);
      acc0[j] = fmaf(xa[2], r2[j], acc0[j]);
      acc0[j] = fmaf(xa[3], r3[j], acc0[j]);
      acc1[j] = fmaf(xb[0], r0[j], acc1[j]);
      acc1[j] = fmaf(xb[1], r1[j], acc1[j]);
      acc1[j] = fmaf(xb[2], r2[j], acc1[j]);
      acc1[j] = fmaf(xb[3], r3[j], acc1[j]);
    }
  }
#pragma unroll
  for (int j=0;j<4;j++){ float bv = B0v[d0+j]; acc0[j] += bv; acc1[j] += bv; }

  // store raw Y0
  {
    size_t r0 = ((size_t)g*KS + k0)*64 + d0;
    *(float4*)&g_y0[r0]      = *(float4*)acc0;
    *(float4*)&g_y0[r0 + 64] = *(float4*)acc1;
  }

  float s[4], q[4];
#pragma unroll
  for (int j=0;j<4;j++){ s[j] = acc0[j]+acc1[j]; q[j] = acc0[j]*acc0[j] + acc1[j]*acc1[j]; }
#pragma unroll
  for (int j=0;j<4;j++){
    s[j] += __shfl_down(s[j],32); s[j] += __shfl_down(s[j],16);
    q[j] += __shfl_down(q[j],32); q[j] += __shfl_down(q[j],16);
  }
  if (lane < 16){
#pragma unroll
    for (int j=0;j<4;j++){ wsum[w][lane*4+j] = s[j]; wsq[w][lane*4+j] = q[j]; }
  }
  __syncthreads();
  if (tid < 64){
    float S = wsum[0][tid]+wsum[1][tid]+wsum[2][tid]+wsum[3][tid];
    float Q = wsq[0][tid]+wsq[1][tid]+wsq[2][tid]+wsq[3][tid];
    int bucket = g & 127;
    atomicAdd(&stats[(size_t)bucket*256 + tid], (double)S);
    atomicAdd(&stats[(size_t)bucket*256 + 128 + tid], (double)Q);
  }
}

// ---------------- K_mlpB: Y0 + BN0/ReLU -> L1 -> Y1 (raw) + stats1 ----------------
__global__ __launch_bounds__(256) void k_mlpB(
    const float* __restrict__ W1, const float* __restrict__ B1v){
  double* stats = g_stats + (size_t)1*128*256;
  const int g = blockIdx.x, tid = threadIdx.x;
  __shared__ __align__(16) float xn[32][68];
  __shared__ __align__(16) float w1s[64][64];
  __shared__ float wsum[4][64], wsq[4][64];

  for (int i = tid; i < 64*64; i += 256) w1s[i>>6][i&63] = W1[i];
  {
    int k = tid >> 3, j = tid & 7;
    const float4* pr = (const float4*)(g_y0 + ((size_t)g*KS + k)*64);
    float4 v0 = pr[j*2], v1 = pr[j*2+1];
    int c0 = j*8;
    xn[k][c0+0] = fmaxf(fmaf(v0.x, g_A[c0+0], g_Bv[c0+0]), 0.f);
    xn[k][c0+1] = fmaxf(fmaf(v0.y, g_A[c0+1], g_Bv[c0+1]), 0.f);
    xn[k][c0+2] = fmaxf(fmaf(v0.z, g_A[c0+2], g_Bv[c0+2]), 0.f);
    xn[k][c0+3] = fmaxf(fmaf(v0.w, g_A[c0+3], g_Bv[c0+3]), 0.f);
    xn[k][c0+4] = fmaxf(fmaf(v1.x, g_A[c0+4], g_Bv[c0+4]), 0.f);
    xn[k][c0+5] = fmaxf(fmaf(v1.y, g_A[c0+5], g_Bv[c0+5]), 0.f);
    xn[k][c0+6] = fmaxf(fmaf(v1.z, g_A[c0+6], g_Bv[c0+6]), 0.f);
    xn[k][c0+7] = fmaxf(fmaf(v1.w, g_A[c0+7], g_Bv[c0+7]), 0.f);
  }
  __syncthreads();

  const int k0 = (tid >> 4) * 2;
  const int d0 = (tid & 15) * 4;
  const int lane = tid & 63, w = tid >> 6;

  float bc0[4] = {0.f,0.f,0.f,0.f};
  float bc1[4] = {0.f,0.f,0.f,0.f};
#pragma unroll
  for (int cq = 0; cq < 16; ++cq){
    const int c = cq*4;
    float xa[4], xb[4], r0[4], r1[4], r2[4], r3[4];
    *(float4*)xa = *(const float4*)&xn[k0][c];
    *(float4*)xb = *(const float4*)&xn[k0+1][c];
    *(float4*)r0 = *(const float4*)&w1s[c+0][d0];
    *(float4*)r1 = *(const float4*)&w1s[c+1][d0];
    *(float4*)r2 = *(const float4*)&w1s[c+2][d0];
    *(float4*)r3 = *(const float4*)&w1s[c+3][d0];
#pragma unroll
    for (int j=0;j<4;j++){
      bc0[j] = fmaf(xa[0], r0[j], bc0[j]);
      bc0[j] = fmaf(xa[1], r1[j], bc0[j]);
      bc0[j] = fmaf(xa[2], r2[j], bc0[j]);
      bc0[j] = fmaf(xa[3], r3[j], bc0[j]);
      bc1[j] = fmaf(xb[0], r0[j], bc1[j]);
      bc1[j] = fmaf(xb[1], r1[j], bc1[j]);
      bc1[j] = fmaf(xb[2], r2[j], bc1[j]);
      bc1[j] = fmaf(xb[3], r3[j], bc1[j]);
    }
  }
#pragma unroll
  for (int j=0;j<4;j++){ float bv = B1v[d0+j]; bc0[j] += bv; bc1[j] += bv; }

  {
    size_t r0 = ((size_t)g*KS + k0)*64 + d0;
    *(float4*)&g_y1[r0]      = *(float4*)bc0;
    *(float4*)&g_y1[r0 + 64] = *(float4*)bc1;
  }

  float s[4], q[4];
#pragma unroll
  for (int j=0;j<4;j++){ s[j] = bc0[j]+bc1[j]; q[j] = bc0[j]*bc0[j] + bc1[j]*bc1[j]; }
#pragma unroll
  for (int j=0;j<4;j++){
    s[j] += __shfl_down(s[j],32); s[j] += __shfl_down(s[j],16);
    q[j] += __shfl_down(q[j],32); q[j] += __shfl_down(q[j],16);
  }
  if (lane < 16){
#pragma unroll
    for (int j=0;j<4;j++){ wsum[w][lane*4+j] = s[j]; wsq[w][lane*4+j] = q[j]; }
  }
  __syncthreads();
  if (tid < 64){
    float S = wsum[0][tid]+wsum[1][tid]+wsum[2][tid]+wsum[3][tid];
    float Q = wsq[0][tid]+wsq[1][tid]+wsq[2][tid]+wsq[3][tid];
    int bucket = g & 127;
    atomicAdd(&stats[(size_t)bucket*256 + tid], (double)S);
    atomicAdd(&stats[(size_t)bucket*256 + 128 + tid], (double)Q);
  }
}

// ---------------- K_mlpC: Y1 + BN1/ReLU -> L2 -> stats2 + max/min ----------------
__global__ __launch_bounds__(256) void k_mlpC(
    const float* __restrict__ W2, const float* __restrict__ B2v){
  double* stats = g_stats + (size_t)2*128*256;
  const int g = blockIdx.x, tid = threadIdx.x;
  __shared__ __align__(16) float xt[32][68];
  __shared__ __align__(16) float w2s[64][128];
  __shared__ float wsum[4][128], wsq[4][128];
  __shared__ float wmx[4][128], wmn[4][128];

  for (int i = tid; i < 64*128; i += 256) w2s[i>>7][i&127] = W2[i];
  {
    int k = tid >> 3, j = tid & 7;
    const float4* pr = (const float4*)(g_y1 + ((size_t)g*KS + k)*64);
    float4 v0 = pr[j*2], v1 = pr[j*2+1];
    int c0 = j*8;
    xt[k][c0+0] = fmaxf(fmaf(v0.x, g_A[64+c0+0], g_Bv[64+c0+0]), 0.f);
    xt[k][c0+1] = fmaxf(fmaf(v0.y, g_A[64+c0+1], g_Bv[64+c0+1]), 0.f);
    xt[k][c0+2] = fmaxf(fmaf(v0.z, g_A[64+c0+2], g_Bv[64+c0+2]), 0.f);
    xt[k][c0+3] = fmaxf(fmaf(v0.w, g_A[64+c0+3], g_Bv[64+c0+3]), 0.f);
    xt[k][c0+4] = fmaxf(fmaf(v1.x, g_A[64+c0+4], g_Bv[64+c0+4]), 0.f);
    xt[k][c0+5] = fmaxf(fmaf(v1.y, g_A[64+c0+5], g_Bv[64+c0+5]), 0.f);
    xt[k][c0+6] = fmaxf(fmaf(v1.z, g_A[64+c0+6], g_Bv[64+c0+6]), 0.f);
    xt[k][c0+7] = fmaxf(fmaf(v1.w, g_A[64+c0+7], g_Bv[64+c0+7]), 0.f);
  }
  __syncthreads();

  const int k0 = (tid >> 4) * 2;
  const int e0 = (tid & 15) * 8;
  const int lane = tid & 63, w = tid >> 6;

  float c0a[8] = {0.f,0.f,0.f,0.f,0.f,0.f,0.f,0.f};
  float c1a[8] = {0.f,0.f,0.f,0.f,0.f,0.f,0.f,0.f};
#pragma unroll
  for (int cq = 0; cq < 16; ++cq){
    const int c = cq*4;
    float xa[4], xb[4], r0[8], r1[8], r2[8], r3[8];
    *(float4*)xa = *(const float4*)&xt[k0][c];
    *(float4*)xb = *(const float4*)&xt[k0+1][c];
    *(float4*)&r0[0] = *(const float4*)&w2s[c+0][e0]; *(float4*)&r0[4] = *(const float4*)&w2s[c+0][e0+4];
    *(float4*)&r1[0] = *(const float4*)&w2s[c+1][e0]; *(float4*)&r1[4] = *(const float4*)&w2s[c+1][e0+4];
    *(float4*)&r2[0] = *(const float4*)&w2s[c+2][e0]; *(float4*)&r2[4] = *(const float4*)&w2s[c+2][e0+4];
    *(float4*)&r3[0] = *(const float4*)&w2s[c+3][e0]; *(float4*)&r3[4] = *(const float4*)&w2s[c+3][e0+4];
#pragma unroll
    for (int j=0;j<8;j++){
      c0a[j] = fmaf(xa[0], r0[j], c0a[j]);
      c0a[j] = fmaf(xa[1], r1[j], c0a[j]);
      c0a[j] = fmaf(xa[2], r2[j], c0a[j]);
      c0a[j] = fmaf(xa[3], r3[j], c0a[j]);
      c1a[j] = fmaf(xb[0], r0[j], c1a[j]);
      c1a[j] = fmaf(xb[1], r1[j], c1a[j]);
      c1a[j] = fmaf(xb[2], r2[j], c1a[j]);
      c1a[j] = fmaf(xb[3], r3[j], c1a[j]);
    }
  }
#pragma unroll
  for (int j=0;j<8;j++){ float bv = B2v[e0+j]; c0a[j] += bv; c1a[j] += bv; }

  float s[8], q[8], mx[8], mn[8];
#pragma unroll
  for (int j=0;j<8;j++){
    s[j] = c0a[j]+c1a[j]; q[j] = c0a[j]*c0a[j] + c1a[j]*c1a[j];
    mx[j] = fmaxf(c0a[j], c1a[j]); mn[j] = fminf(c0a[j], c1a[j]);
  }
#pragma unroll
  for (int j=0;j<8;j++){
    s[j] += __shfl_down(s[j],32); s[j] += __shfl_down(s[j],16);
    q[j] += __shfl_down(q[j],32); q[j] += __shfl_down(q[j],16);
    mx[j] = fmaxf(mx[j], __shfl_xor(mx[j],16)); mx[j] = fmaxf(mx[j], __shfl_xor(mx[j],32));
    mn[j] = fminf(mn[j], __shfl_xor(mn[j],16)); mn[j] = fminf(mn[j], __shfl_xor(mn[j],32));
  }
  if (lane < 16){
#pragma unroll
    for (int j=0;j<8;j++){
      wsum[w][lane*8+j] = s[j]; wsq[w][lane*8+j] = q[j];
      wmx[w][lane*8+j] = mx[j]; wmn[w][lane*8+j] = mn[j];
    }
  }
  __syncthreads();
  if (tid < 128){
    float S = wsum[0][tid]+wsum[1][tid]+wsum[2][tid]+wsum[3][tid];
    float Q = wsq[0][tid]+wsq[1][tid]+wsq[2][tid]+wsq[3][tid];
    float MX = fmaxf(fmaxf(wmx[0][tid],wmx[1][tid]), fmaxf(wmx[2][tid],wmx[3][tid]));
    float MN = fminf(fminf(wmn[0][tid],wmn[1][tid]), fminf(wmn[2][tid],wmn[3][tid]));
    g_mmax[(size_t)g*128 + tid] = MX;
    g_mmin[(size_t)g*128 + tid] = MN;
    int bucket = g & 127;
    atomicAdd(&stats[(size_t)bucket*256 + tid], (double)S);
    atomicAdd(&stats[(size_t)bucket*256 + 128 + tid], (double)Q);
  }
}

// ---------------- K_stats ----------------
__global__ void k_stats(int stage, const float* __restrict__ gamma,
                        const float* __restrict__ beta, int aoff, int cout){
  int c = threadIdx.x;
  if (c >= cout) return;
  const double* stats = g_stats + (size_t)stage*128*256;
  double S=0.0, Q=0.0;
  for (int k=0;k<128;k++){ S += stats[(size_t)k*256 + c]; Q += stats[(size_t)k*256 + 128 + c]; }
  const double M = (double)MROWS;
  double mean = S / M;
  double var  = Q / M - mean*mean;
  double inv  = 1.0 / sqrt(var + 1e-5);
  double a    = (double)gamma[c] * inv;
  g_A[aoff+c]  = (float)a;
  g_Bv[aoff+c] = (float)((double)beta[c] - mean * a);
}

// ---------------- K_final ----------------
__global__ __launch_bounds__(256) void k_final(float* __restrict__ outp){
  int idx = blockIdx.x*256 + threadIdx.x;
  int d = idx & 127;
  float a = g_A[128+d], b = g_Bv[128+d];
  float y = (a >= 0.f) ? g_mmax[idx] : g_mmin[idx];
  float v = fmaf(y, a, b);
  outp[idx] = fmaxf(v, 0.f);
}

extern "C" void kernel_launch(void* const* d_in, const int* in_sizes, int n_in,
                              void* d_out, int out_size, void* d_ws, size_t ws_size,
                              hipStream_t stream) {
  (void)in_sizes; (void)n_in; (void)out_size; (void)d_ws; (void)ws_size;
  const float* xyz    = (const float*)d_in[0];
  const float* points = (const float*)d_in[1];
  const int*   start  = (const int*)d_in[2];
  const float* W0 = (const float*)d_in[3];  const float* b0 = (const float*)d_in[4];
  const float* g0 = (const float*)d_in[5];  const float* be0= (const float*)d_in[6];
  const float* W1 = (const float*)d_in[7];  const float* b1 = (const float*)d_in[8];
  const float* g1 = (const float*)d_in[9];  const float* be1= (const float*)d_in[10];
  const float* W2 = (const float*)d_in[11]; const float* b2 = (const float*)d_in[12];
  const float* g2 = (const float*)d_in[13]; const float* be2= (const float*)d_in[14];

  float* out_xyz = (float*)d_out;
  float* out_pts = (float*)d_out + (size_t)NBATCH*SG*3;

  k_zero <<<384, 256, 0, stream>>>();
  k_pre  <<<256, 256, 0, stream>>>(xyz);
  k_fps  <<<NBATCH, 256, 0, stream>>>(start, out_xyz);
  k_ball <<<4096, 256, 0, stream>>>();

  k_mlpA<<<NGRP, 256, 0, stream>>>(points, W0, b0);
  k_stats<<<1, 128, 0, stream>>>(0, g0, be0, 0, 64);
  k_mlpB<<<NGRP, 256, 0, stream>>>(W1, b1);
  k_stats<<<1, 128, 0, stream>>>(1, g1, be1, 64, 64);
  k_mlpC<<<NGRP, 256, 0, stream>>>(W2, b2);
  k_stats<<<1, 128, 0, stream>>>(2, g2, be2, 128, 128);
  k_final<<<8192, 256, 0, stream>>>(out_pts);
}